// Round 2
// baseline (9719.278 us; speedup 1.0000x reference)
//
#include <hip/hip_runtime.h>
#include <math.h>

#define NB 8192
#define S_ 45
#define D_ 64
#define FF_ 256
#define LD 68      // padded row stride for [45][64] LDS tiles (breaks 4-way bank conflicts)
#define LDF 132    // padded row stride for FFN half-tile [45][128]

__global__ void pe_kernel(float* __restrict__ pe) {
    int idx = blockIdx.x * 256 + threadIdx.x;
    if (idx < S_ * D_) {
        int s = idx / D_, d = idx % D_;
        float div = expf(-logf(10000.0f) * (float)(d & ~1) / (float)D_);
        float ang = (float)s * div;
        pe[idx] = (d & 1) ? cosf(ang) : sinf(ang);
    }
}

__device__ inline float dot8(const float4 a1, const float4 a2,
                             const float4 b1, const float4 b2) {
    return a1.x * b1.x + a1.y * b1.y + a1.z * b1.z + a1.w * b1.w +
           a2.x * b2.x + a2.y * b2.y + a2.z * b2.z + a2.w * b2.w;
}

__device__ inline void fma4x4(float4& acc, const float4 hv,
                              const float4 w0, const float4 w1,
                              const float4 w2, const float4 w3) {
    acc.x += hv.x * w0.x + hv.y * w1.x + hv.z * w2.x + hv.w * w3.x;
    acc.y += hv.x * w0.y + hv.y * w1.y + hv.z * w2.y + hv.w * w3.y;
    acc.z += hv.x * w0.z + hv.y * w1.z + hv.z * w2.z + hv.w * w3.z;
    acc.w += hv.x * w0.w + hv.y * w1.w + hv.z * w2.w + hv.w * w3.w;
}

__launch_bounds__(512, 4)
__global__ void encoder_kernel(
    const float* __restrict__ x,
    const float* __restrict__ Wq, const float* __restrict__ bq,
    const float* __restrict__ Wk, const float* __restrict__ bk,
    const float* __restrict__ Wv, const float* __restrict__ bv,
    const float* __restrict__ Wo, const float* __restrict__ bo,
    const float* __restrict__ ln1g, const float* __restrict__ ln1b,
    const float* __restrict__ W1, const float* __restrict__ b1,
    const float* __restrict__ W2, const float* __restrict__ b2,
    const float* __restrict__ ln2g, const float* __restrict__ ln2b,
    const float* __restrict__ pe,
    float* __restrict__ out)
{
    // LDS (12240 floats = 48.96 KB):
    //   h [45][LD] : x+pe (residual1) -> h2 (post-LN1) -> t2 (pre-LN2)
    //   U = q|k|v, each [45][LD]. o overlays k after attention.
    //   FFN half-tile f[45][LDF] overlays q+k.
    __shared__ float h[S_ * LD];
    __shared__ float U[3 * S_ * LD];
    float* qs = U;
    float* ks = U + S_ * LD;
    float* vs = U + 2 * S_ * LD;
    float* os = ks;   // o overlays k (k dead after attention pass B)
    float* fs = U;    // f overlays q+k (dead after LN1 / step 4)

    const int t = threadIdx.x;
    const int b = blockIdx.x;

    // ---- 1. h = x + pe ------------------------------------------------
    {
        const float4* x4 = (const float4*)(x + (size_t)b * (S_ * D_));
        const float4* p4 = (const float4*)pe;
        for (int idx = t; idx < S_ * D_ / 4; idx += 512) {
            int r = idx >> 4, c4 = (idx & 15) << 2;
            float4 a = x4[idx], p = p4[idx];
            *(float4*)&h[r * LD + c4] =
                make_float4(a.x + p.x, a.y + p.y, a.z + p.z, a.w + p.w);
        }
    }
    __syncthreads();

    // ---- 2. fused Q,K,V projections ----------------------------------
    // thread: col c = t&63, row slots r = (t>>6) + 8*i, i<6
    {
        const int c = t & 63, rg = t >> 6;
        float aq[6], ak[6], av[6];
        #pragma unroll
        for (int i = 0; i < 6; ++i) { aq[i] = 0.f; ak[i] = 0.f; av[i] = 0.f; }
        for (int k4 = 0; k4 < D_; k4 += 4) {
            float4 hv[6];
            #pragma unroll
            for (int i = 0; i < 6; ++i) {
                int r = rg + 8 * i;
                hv[i] = (r < S_) ? *(const float4*)&h[r * LD + k4]
                                 : make_float4(0.f, 0.f, 0.f, 0.f);
            }
            float wq0 = Wq[(k4 + 0) * 64 + c], wq1 = Wq[(k4 + 1) * 64 + c];
            float wq2 = Wq[(k4 + 2) * 64 + c], wq3 = Wq[(k4 + 3) * 64 + c];
            float wk0 = Wk[(k4 + 0) * 64 + c], wk1 = Wk[(k4 + 1) * 64 + c];
            float wk2 = Wk[(k4 + 2) * 64 + c], wk3 = Wk[(k4 + 3) * 64 + c];
            float wv0 = Wv[(k4 + 0) * 64 + c], wv1 = Wv[(k4 + 1) * 64 + c];
            float wv2 = Wv[(k4 + 2) * 64 + c], wv3 = Wv[(k4 + 3) * 64 + c];
            #pragma unroll
            for (int i = 0; i < 6; ++i) {
                aq[i] += hv[i].x * wq0 + hv[i].y * wq1 + hv[i].z * wq2 + hv[i].w * wq3;
                ak[i] += hv[i].x * wk0 + hv[i].y * wk1 + hv[i].z * wk2 + hv[i].w * wk3;
                av[i] += hv[i].x * wv0 + hv[i].y * wv1 + hv[i].z * wv2 + hv[i].w * wv3;
            }
        }
        float bqc = bq[c], bkc = bk[c], bvc = bv[c];
        #pragma unroll
        for (int i = 0; i < 6; ++i) {
            int r = rg + 8 * i;
            if (r < S_) {
                qs[r * LD + c] = aq[i] + bqc;
                ks[r * LD + c] = ak[i] + bkc;
                vs[r * LD + c] = av[i] + bvc;
            }
        }
    }
    __syncthreads();

    // ---- 3. attention: one (q-row, head) pair per thread, 2-pass ------
    // (no score array -> no spills; dots recomputed in pass B)
    {
        int qr = 0, hd = 0;
        float4 o1 = make_float4(0.f, 0.f, 0.f, 0.f);
        float4 o2 = make_float4(0.f, 0.f, 0.f, 0.f);
        const bool act = (t < S_ * 8);
        if (act) {
            qr = t >> 3;
            hd = (t & 7) << 3;
            const float scale = 0.35355339059327373f;  // 1/sqrt(8)
            float4 qa = *(const float4*)&qs[qr * LD + hd];
            float4 qb = *(const float4*)&qs[qr * LD + hd + 4];
            float m = -3.0e38f;
            #pragma unroll 5
            for (int k = 0; k < S_; ++k) {
                float4 ka = *(const float4*)&ks[k * LD + hd];
                float4 kb = *(const float4*)&ks[k * LD + hd + 4];
                m = fmaxf(m, dot8(qa, qb, ka, kb));
            }
            float l = 0.f;
            #pragma unroll 5
            for (int k = 0; k < S_; ++k) {
                float4 ka = *(const float4*)&ks[k * LD + hd];
                float4 kb = *(const float4*)&ks[k * LD + hd + 4];
                float p = __expf((dot8(qa, qb, ka, kb) - m) * scale);
                l += p;
                float4 va = *(const float4*)&vs[k * LD + hd];
                float4 vb = *(const float4*)&vs[k * LD + hd + 4];
                o1.x += p * va.x; o1.y += p * va.y; o1.z += p * va.z; o1.w += p * va.w;
                o2.x += p * vb.x; o2.y += p * vb.y; o2.z += p * vb.z; o2.w += p * vb.w;
            }
            float inv = 1.0f / l;
            o1.x *= inv; o1.y *= inv; o1.z *= inv; o1.w *= inv;
            o2.x *= inv; o2.y *= inv; o2.z *= inv; o2.w *= inv;
        }
        __syncthreads();               // all reads of k done before o overlays it
        if (act) {
            *(float4*)&os[qr * LD + hd]     = o1;
            *(float4*)&os[qr * LD + hd + 4] = o2;
        }
    }
    __syncthreads();

    // ---- 4. t1 = o @ Wo + bo + h (residual) -> q-space ----------------
    {
        const int c0 = (t & 15) << 2, rg = t >> 4;
        float4 acc[2];
        acc[0] = make_float4(0.f, 0.f, 0.f, 0.f);
        acc[1] = make_float4(0.f, 0.f, 0.f, 0.f);
        for (int k4 = 0; k4 < D_; k4 += 4) {
            float4 ov[2];
            #pragma unroll
            for (int i = 0; i < 2; ++i) {
                int r = rg + 32 * i;
                ov[i] = (r < S_) ? *(const float4*)&os[r * LD + k4]
                                 : make_float4(0.f, 0.f, 0.f, 0.f);
            }
            float4 w0 = *(const float4*)&Wo[(k4 + 0) * 64 + c0];
            float4 w1 = *(const float4*)&Wo[(k4 + 1) * 64 + c0];
            float4 w2 = *(const float4*)&Wo[(k4 + 2) * 64 + c0];
            float4 w3 = *(const float4*)&Wo[(k4 + 3) * 64 + c0];
            fma4x4(acc[0], ov[0], w0, w1, w2, w3);
            fma4x4(acc[1], ov[1], w0, w1, w2, w3);
        }
        float4 bo4 = *(const float4*)&bo[c0];
        #pragma unroll
        for (int i = 0; i < 2; ++i) {
            int r = rg + 32 * i;
            if (r < S_) {
                float4 hr = *(const float4*)&h[r * LD + c0];
                float4 o;
                o.x = acc[i].x + bo4.x + hr.x;
                o.y = acc[i].y + bo4.y + hr.y;
                o.z = acc[i].z + bo4.z + hr.z;
                o.w = acc[i].w + bo4.w + hr.w;
                *(float4*)&qs[r * LD + c0] = o;
            }
        }
    }
    __syncthreads();

    // ---- 5. LN1: t1 (q-space) -> h2 (h-space) -------------------------
    {
        const int wv = t >> 6, d = t & 63;
        const float g = ln1g[d], bb = ln1b[d];
        for (int i = 0; i < 6; ++i) {
            int r = wv + 8 * i;
            if (r < S_) {
                float v = qs[r * LD + d];
                float s = v, s2 = v * v;
                #pragma unroll
                for (int off = 32; off; off >>= 1) {
                    s  += __shfl_xor(s, off);
                    s2 += __shfl_xor(s2, off);
                }
                float mean = s * (1.0f / 64.0f);
                float var  = s2 * (1.0f / 64.0f) - mean * mean;
                float nv = (v - mean) * rsqrtf(var + 1e-5f);
                h[r * LD + d] = nv * g + bb;
            }
        }
    }
    __syncthreads();

    // ---- 6+7. FFN in two 128-wide halves; FFN2 accumulates in regs ----
    const int f_c0 = (t & 31) << 2, f_rg = t >> 5;   // FFN1: 128 cols x 16 row-threads
    const int g_c0 = (t & 15) << 2, g_rg = t >> 4;   // FFN2: 64 cols x 32 row-threads
    float4 facc[2];
    facc[0] = make_float4(0.f, 0.f, 0.f, 0.f);
    facc[1] = make_float4(0.f, 0.f, 0.f, 0.f);
    for (int half = 0; half < 2; ++half) {
        // FFN1: f = relu(h2 @ W1[:, half*128 ..] + b1)
        {
            float4 a1[3];
            #pragma unroll
            for (int i = 0; i < 3; ++i) a1[i] = make_float4(0.f, 0.f, 0.f, 0.f);
            for (int k4 = 0; k4 < D_; k4 += 4) {
                float4 hv[3];
                #pragma unroll
                for (int i = 0; i < 3; ++i) {
                    int r = f_rg + 16 * i;
                    hv[i] = (r < S_) ? *(const float4*)&h[r * LD + k4]
                                     : make_float4(0.f, 0.f, 0.f, 0.f);
                }
                float4 w0 = *(const float4*)&W1[(k4 + 0) * FF_ + half * 128 + f_c0];
                float4 w1 = *(const float4*)&W1[(k4 + 1) * FF_ + half * 128 + f_c0];
                float4 w2 = *(const float4*)&W1[(k4 + 2) * FF_ + half * 128 + f_c0];
                float4 w3 = *(const float4*)&W1[(k4 + 3) * FF_ + half * 128 + f_c0];
                fma4x4(a1[0], hv[0], w0, w1, w2, w3);
                fma4x4(a1[1], hv[1], w0, w1, w2, w3);
                fma4x4(a1[2], hv[2], w0, w1, w2, w3);
            }
            float4 bias = *(const float4*)&b1[half * 128 + f_c0];
            #pragma unroll
            for (int i = 0; i < 3; ++i) {
                int r = f_rg + 16 * i;
                if (r < S_) {
                    float4 o;
                    o.x = fmaxf(a1[i].x + bias.x, 0.f);
                    o.y = fmaxf(a1[i].y + bias.y, 0.f);
                    o.z = fmaxf(a1[i].z + bias.z, 0.f);
                    o.w = fmaxf(a1[i].w + bias.w, 0.f);
                    *(float4*)&fs[r * LDF + f_c0] = o;
                }
            }
        }
        __syncthreads();
        // FFN2 partial: facc += f @ W2[half*128 .., :]
        {
            for (int k4 = 0; k4 < 128; k4 += 4) {
                float4 fv[2];
                #pragma unroll
                for (int i = 0; i < 2; ++i) {
                    int r = g_rg + 32 * i;
                    fv[i] = (r < S_) ? *(const float4*)&fs[r * LDF + k4]
                                     : make_float4(0.f, 0.f, 0.f, 0.f);
                }
                float4 w0 = *(const float4*)&W2[(half * 128 + k4 + 0) * 64 + g_c0];
                float4 w1 = *(const float4*)&W2[(half * 128 + k4 + 1) * 64 + g_c0];
                float4 w2 = *(const float4*)&W2[(half * 128 + k4 + 2) * 64 + g_c0];
                float4 w3 = *(const float4*)&W2[(half * 128 + k4 + 3) * 64 + g_c0];
                fma4x4(facc[0], fv[0], w0, w1, w2, w3);
                fma4x4(facc[1], fv[1], w0, w1, w2, w3);
            }
        }
        __syncthreads();   // before next half overwrites fs
    }
    // FFN2 epilogue: t2 = facc + b2 + h2 -> h-space
    {
        float4 b24 = *(const float4*)&b2[g_c0];
        #pragma unroll
        for (int i = 0; i < 2; ++i) {
            int r = g_rg + 32 * i;
            if (r < S_) {
                float4 hr = *(const float4*)&h[r * LD + g_c0];
                float4 o;
                o.x = facc[i].x + b24.x + hr.x;
                o.y = facc[i].y + b24.y + hr.y;
                o.z = facc[i].z + b24.z + hr.z;
                o.w = facc[i].w + b24.w + hr.w;
                *(float4*)&h[r * LD + g_c0] = o;
            }
        }
    }
    __syncthreads();

    // ---- 8. LN2: t2 (h-space) -> out ----------------------------------
    {
        const int wv = t >> 6, d = t & 63;
        const float g = ln2g[d], bb = ln2b[d];
        for (int i = 0; i < 6; ++i) {
            int r = wv + 8 * i;
            if (r < S_) {
                float v = h[r * LD + d];
                float s = v, s2 = v * v;
                #pragma unroll
                for (int off = 32; off; off >>= 1) {
                    s  += __shfl_xor(s, off);
                    s2 += __shfl_xor(s2, off);
                }
                float mean = s * (1.0f / 64.0f);
                float var  = s2 * (1.0f / 64.0f) - mean * mean;
                float nv = (v - mean) * rsqrtf(var + 1e-5f);
                out[(size_t)b * (S_ * D_) + r * 64 + d] = nv * g + bb;
            }
        }
    }
}

extern "C" void kernel_launch(void* const* d_in, const int* in_sizes, int n_in,
                              void* d_out, int out_size, void* d_ws, size_t ws_size,
                              hipStream_t stream) {
    const float* x    = (const float*)d_in[0];
    const float* Wq   = (const float*)d_in[1];
    const float* bq   = (const float*)d_in[2];
    const float* Wk   = (const float*)d_in[3];
    const float* bk   = (const float*)d_in[4];
    const float* Wv   = (const float*)d_in[5];
    const float* bv   = (const float*)d_in[6];
    const float* Wo   = (const float*)d_in[7];
    const float* bo   = (const float*)d_in[8];
    const float* ln1g = (const float*)d_in[9];
    const float* ln1b = (const float*)d_in[10];
    const float* W1   = (const float*)d_in[11];
    const float* b1   = (const float*)d_in[12];
    const float* W2   = (const float*)d_in[13];
    const float* b2   = (const float*)d_in[14];
    const float* ln2g = (const float*)d_in[15];
    const float* ln2b = (const float*)d_in[16];
    float* out = (float*)d_out;
    float* pe  = (float*)d_ws;

    hipLaunchKernelGGL(pe_kernel, dim3((S_ * D_ + 255) / 256), dim3(256), 0, stream, pe);
    hipLaunchKernelGGL(encoder_kernel, dim3(NB), dim3(512), 0, stream,
                       x, Wq, bq, Wk, bk, Wv, bv, Wo, bo,
                       ln1g, ln1b, W1, b1, W2, b2, ln2g, ln2b, pe, out);
}

// Round 3
// 6817.882 us; speedup vs baseline: 1.4256x; 1.4256x over previous
//
#include <hip/hip_runtime.h>
#include <math.h>

#define NB 8192
#define S_ 45
#define D_ 64
#define FF_ 256
#define LD 68      // padded row stride for [45][64] LDS tiles (breaks 4-way bank conflicts)
#define LDF 132    // padded row stride for FFN half-tile [45][128]

__global__ void pe_kernel(float* __restrict__ pe) {
    int idx = blockIdx.x * 256 + threadIdx.x;
    if (idx < S_ * D_) {
        int s = idx / D_, d = idx % D_;
        float div = expf(-logf(10000.0f) * (float)(d & ~1) / (float)D_);
        float ang = (float)s * div;
        pe[idx] = (d & 1) ? cosf(ang) : sinf(ang);
    }
}

__device__ inline float dot8(const float4 a1, const float4 a2,
                             const float4 b1, const float4 b2) {
    return a1.x * b1.x + a1.y * b1.y + a1.z * b1.z + a1.w * b1.w +
           a2.x * b2.x + a2.y * b2.y + a2.z * b2.z + a2.w * b2.w;
}

__device__ inline void fma4x4(float4& acc, const float4 hv,
                              const float4 w0, const float4 w1,
                              const float4 w2, const float4 w3) {
    acc.x += hv.x * w0.x + hv.y * w1.x + hv.z * w2.x + hv.w * w3.x;
    acc.y += hv.x * w0.y + hv.y * w1.y + hv.z * w2.y + hv.w * w3.y;
    acc.z += hv.x * w0.z + hv.y * w1.z + hv.z * w2.z + hv.w * w3.z;
    acc.w += hv.x * w0.w + hv.y * w1.w + hv.z * w2.w + hv.w * w3.w;
}

// (512,2): min 2 waves/EU -> VGPR cap 256. Round-2's (512,4) forced a 64-VGPR
// cap -> 17 GB of scratch writes. We want ~100-128 VGPRs, zero spill.
__launch_bounds__(512, 2)
__global__ void encoder_kernel(
    const float* __restrict__ x,
    const float* __restrict__ Wq, const float* __restrict__ bq,
    const float* __restrict__ Wk, const float* __restrict__ bk,
    const float* __restrict__ Wv, const float* __restrict__ bv,
    const float* __restrict__ Wo, const float* __restrict__ bo,
    const float* __restrict__ ln1g, const float* __restrict__ ln1b,
    const float* __restrict__ W1, const float* __restrict__ b1,
    const float* __restrict__ W2, const float* __restrict__ b2,
    const float* __restrict__ ln2g, const float* __restrict__ ln2b,
    const float* __restrict__ pe,
    float* __restrict__ out)
{
    __shared__ float h[S_ * LD];
    __shared__ float U[3 * S_ * LD];
    float* qs = U;
    float* ks = U + S_ * LD;
    float* vs = U + 2 * S_ * LD;
    float* os = ks;   // o overlays k (k dead after attention pass B)
    float* fs = U;    // f overlays q+k (dead after LN1 / step 4)

    const int t = threadIdx.x;
    const int b = blockIdx.x;

    // ---- 1. h = x + pe ------------------------------------------------
    {
        const float4* x4 = (const float4*)(x + (size_t)b * (S_ * D_));
        const float4* p4 = (const float4*)pe;
        for (int idx = t; idx < S_ * D_ / 4; idx += 512) {
            int r = idx >> 4, c4 = (idx & 15) << 2;
            float4 a = x4[idx], p = p4[idx];
            *(float4*)&h[r * LD + c4] =
                make_float4(a.x + p.x, a.y + p.y, a.z + p.z, a.w + p.w);
        }
    }
    __syncthreads();

    // ---- 2. fused Q,K,V projections ----------------------------------
    {
        const int c = t & 63, rg = t >> 6;
        float aq[6], ak[6], av[6];
        #pragma unroll
        for (int i = 0; i < 6; ++i) { aq[i] = 0.f; ak[i] = 0.f; av[i] = 0.f; }
        for (int k4 = 0; k4 < D_; k4 += 4) {
            float4 hv[6];
            #pragma unroll
            for (int i = 0; i < 6; ++i) {
                int r = rg + 8 * i;
                hv[i] = (r < S_) ? *(const float4*)&h[r * LD + k4]
                                 : make_float4(0.f, 0.f, 0.f, 0.f);
            }
            float wq0 = Wq[(k4 + 0) * 64 + c], wq1 = Wq[(k4 + 1) * 64 + c];
            float wq2 = Wq[(k4 + 2) * 64 + c], wq3 = Wq[(k4 + 3) * 64 + c];
            float wk0 = Wk[(k4 + 0) * 64 + c], wk1 = Wk[(k4 + 1) * 64 + c];
            float wk2 = Wk[(k4 + 2) * 64 + c], wk3 = Wk[(k4 + 3) * 64 + c];
            float wv0 = Wv[(k4 + 0) * 64 + c], wv1 = Wv[(k4 + 1) * 64 + c];
            float wv2 = Wv[(k4 + 2) * 64 + c], wv3 = Wv[(k4 + 3) * 64 + c];
            #pragma unroll
            for (int i = 0; i < 6; ++i) {
                aq[i] += hv[i].x * wq0 + hv[i].y * wq1 + hv[i].z * wq2 + hv[i].w * wq3;
                ak[i] += hv[i].x * wk0 + hv[i].y * wk1 + hv[i].z * wk2 + hv[i].w * wk3;
                av[i] += hv[i].x * wv0 + hv[i].y * wv1 + hv[i].z * wv2 + hv[i].w * wv3;
            }
        }
        float bqc = bq[c], bkc = bk[c], bvc = bv[c];
        #pragma unroll
        for (int i = 0; i < 6; ++i) {
            int r = rg + 8 * i;
            if (r < S_) {
                qs[r * LD + c] = aq[i] + bqc;
                ks[r * LD + c] = ak[i] + bkc;
                vs[r * LD + c] = av[i] + bvc;
            }
        }
    }
    __syncthreads();

    // ---- 3. attention: one (q-row, head) per thread, 2-pass -----------
    {
        int qr = 0, hd = 0;
        float4 o1 = make_float4(0.f, 0.f, 0.f, 0.f);
        float4 o2 = make_float4(0.f, 0.f, 0.f, 0.f);
        const bool act = (t < S_ * 8);
        if (act) {
            qr = t >> 3;
            hd = (t & 7) << 3;
            const float scale = 0.35355339059327373f;  // 1/sqrt(8)
            float4 qa = *(const float4*)&qs[qr * LD + hd];
            float4 qb = *(const float4*)&qs[qr * LD + hd + 4];
            float m = -3.0e38f;
            #pragma unroll 5
            for (int k = 0; k < S_; ++k) {
                float4 ka = *(const float4*)&ks[k * LD + hd];
                float4 kb = *(const float4*)&ks[k * LD + hd + 4];
                m = fmaxf(m, dot8(qa, qb, ka, kb));
            }
            float l = 0.f;
            #pragma unroll 5
            for (int k = 0; k < S_; ++k) {
                float4 ka = *(const float4*)&ks[k * LD + hd];
                float4 kb = *(const float4*)&ks[k * LD + hd + 4];
                float p = __expf((dot8(qa, qb, ka, kb) - m) * scale);
                l += p;
                float4 va = *(const float4*)&vs[k * LD + hd];
                float4 vb = *(const float4*)&vs[k * LD + hd + 4];
                o1.x += p * va.x; o1.y += p * va.y; o1.z += p * va.z; o1.w += p * va.w;
                o2.x += p * vb.x; o2.y += p * vb.y; o2.z += p * vb.z; o2.w += p * vb.w;
            }
            float inv = 1.0f / l;
            o1.x *= inv; o1.y *= inv; o1.z *= inv; o1.w *= inv;
            o2.x *= inv; o2.y *= inv; o2.z *= inv; o2.w *= inv;
        }
        __syncthreads();               // all reads of k done before o overlays it
        if (act) {
            *(float4*)&os[qr * LD + hd]     = o1;
            *(float4*)&os[qr * LD + hd + 4] = o2;
        }
    }
    __syncthreads();

    // ---- 4. t1 = o @ Wo + bo + h (residual) -> q-space ----------------
    {
        const int c0 = (t & 15) << 2, rg = t >> 4;
        float4 acc[2];
        acc[0] = make_float4(0.f, 0.f, 0.f, 0.f);
        acc[1] = make_float4(0.f, 0.f, 0.f, 0.f);
        for (int k4 = 0; k4 < D_; k4 += 4) {
            float4 ov[2];
            #pragma unroll
            for (int i = 0; i < 2; ++i) {
                int r = rg + 32 * i;
                ov[i] = (r < S_) ? *(const float4*)&os[r * LD + k4]
                                 : make_float4(0.f, 0.f, 0.f, 0.f);
            }
            float4 w0 = *(const float4*)&Wo[(k4 + 0) * 64 + c0];
            float4 w1 = *(const float4*)&Wo[(k4 + 1) * 64 + c0];
            float4 w2 = *(const float4*)&Wo[(k4 + 2) * 64 + c0];
            float4 w3 = *(const float4*)&Wo[(k4 + 3) * 64 + c0];
            fma4x4(acc[0], ov[0], w0, w1, w2, w3);
            fma4x4(acc[1], ov[1], w0, w1, w2, w3);
        }
        float4 bo4 = *(const float4*)&bo[c0];
        #pragma unroll
        for (int i = 0; i < 2; ++i) {
            int r = rg + 32 * i;
            if (r < S_) {
                float4 hr = *(const float4*)&h[r * LD + c0];
                float4 o;
                o.x = acc[i].x + bo4.x + hr.x;
                o.y = acc[i].y + bo4.y + hr.y;
                o.z = acc[i].z + bo4.z + hr.z;
                o.w = acc[i].w + bo4.w + hr.w;
                *(float4*)&qs[r * LD + c0] = o;
            }
        }
    }
    __syncthreads();

    // ---- 5. LN1: t1 (q-space) -> h2 (h-space) -------------------------
    {
        const int wv = t >> 6, d = t & 63;
        const float g = ln1g[d], bb = ln1b[d];
        for (int i = 0; i < 6; ++i) {
            int r = wv + 8 * i;
            if (r < S_) {
                float v = qs[r * LD + d];
                float s = v, s2 = v * v;
                #pragma unroll
                for (int off = 32; off; off >>= 1) {
                    s  += __shfl_xor(s, off);
                    s2 += __shfl_xor(s2, off);
                }
                float mean = s * (1.0f / 64.0f);
                float var  = s2 * (1.0f / 64.0f) - mean * mean;
                float nv = (v - mean) * rsqrtf(var + 1e-5f);
                h[r * LD + d] = nv * g + bb;
            }
        }
    }
    __syncthreads();

    // ---- 6+7. FFN in two 128-wide halves; FFN2 accumulates in regs ----
    const int f_c0 = (t & 31) << 2, f_rg = t >> 5;
    const int g_c0 = (t & 15) << 2, g_rg = t >> 4;
    float4 facc[2];
    facc[0] = make_float4(0.f, 0.f, 0.f, 0.f);
    facc[1] = make_float4(0.f, 0.f, 0.f, 0.f);
    for (int half = 0; half < 2; ++half) {
        // FFN1: f = relu(h2 @ W1[:, half*128 ..] + b1)
        {
            float4 a1[3];
            #pragma unroll
            for (int i = 0; i < 3; ++i) a1[i] = make_float4(0.f, 0.f, 0.f, 0.f);
            for (int k4 = 0; k4 < D_; k4 += 4) {
                float4 hv[3];
                #pragma unroll
                for (int i = 0; i < 3; ++i) {
                    int r = f_rg + 16 * i;
                    hv[i] = (r < S_) ? *(const float4*)&h[r * LD + k4]
                                     : make_float4(0.f, 0.f, 0.f, 0.f);
                }
                float4 w0 = *(const float4*)&W1[(k4 + 0) * FF_ + half * 128 + f_c0];
                float4 w1 = *(const float4*)&W1[(k4 + 1) * FF_ + half * 128 + f_c0];
                float4 w2 = *(const float4*)&W1[(k4 + 2) * FF_ + half * 128 + f_c0];
                float4 w3 = *(const float4*)&W1[(k4 + 3) * FF_ + half * 128 + f_c0];
                fma4x4(a1[0], hv[0], w0, w1, w2, w3);
                fma4x4(a1[1], hv[1], w0, w1, w2, w3);
                fma4x4(a1[2], hv[2], w0, w1, w2, w3);
            }
            float4 bias = *(const float4*)&b1[half * 128 + f_c0];
            #pragma unroll
            for (int i = 0; i < 3; ++i) {
                int r = f_rg + 16 * i;
                if (r < S_) {
                    float4 o;
                    o.x = fmaxf(a1[i].x + bias.x, 0.f);
                    o.y = fmaxf(a1[i].y + bias.y, 0.f);
                    o.z = fmaxf(a1[i].z + bias.z, 0.f);
                    o.w = fmaxf(a1[i].w + bias.w, 0.f);
                    *(float4*)&fs[r * LDF + f_c0] = o;
                }
            }
        }
        __syncthreads();
        // FFN2 partial: facc += f @ W2[half*128 .., :]
        {
            for (int k4 = 0; k4 < 128; k4 += 4) {
                float4 fv[2];
                #pragma unroll
                for (int i = 0; i < 2; ++i) {
                    int r = g_rg + 32 * i;
                    fv[i] = (r < S_) ? *(const float4*)&fs[r * LDF + k4]
                                     : make_float4(0.f, 0.f, 0.f, 0.f);
                }
                float4 w0 = *(const float4*)&W2[(half * 128 + k4 + 0) * 64 + g_c0];
                float4 w1 = *(const float4*)&W2[(half * 128 + k4 + 1) * 64 + g_c0];
                float4 w2 = *(const float4*)&W2[(half * 128 + k4 + 2) * 64 + g_c0];
                float4 w3 = *(const float4*)&W2[(half * 128 + k4 + 3) * 64 + g_c0];
                fma4x4(facc[0], fv[0], w0, w1, w2, w3);
                fma4x4(facc[1], fv[1], w0, w1, w2, w3);
            }
        }
        __syncthreads();   // before next half overwrites fs
    }
    // FFN2 epilogue: t2 = facc + b2 + h2 -> h-space
    {
        float4 b24 = *(const float4*)&b2[g_c0];
        #pragma unroll
        for (int i = 0; i < 2; ++i) {
            int r = g_rg + 32 * i;
            if (r < S_) {
                float4 hr = *(const float4*)&h[r * LD + g_c0];
                float4 o;
                o.x = facc[i].x + b24.x + hr.x;
                o.y = facc[i].y + b24.y + hr.y;
                o.z = facc[i].z + b24.z + hr.z;
                o.w = facc[i].w + b24.w + hr.w;
                *(float4*)&h[r * LD + g_c0] = o;
            }
        }
    }
    __syncthreads();

    // ---- 8. LN2: t2 (h-space) -> out ----------------------------------
    {
        const int wv = t >> 6, d = t & 63;
        const float g = ln2g[d], bb = ln2b[d];
        for (int i = 0; i < 6; ++i) {
            int r = wv + 8 * i;
            if (r < S_) {
                float v = h[r * LD + d];
                float s = v, s2 = v * v;
                #pragma unroll
                for (int off = 32; off; off >>= 1) {
                    s  += __shfl_xor(s, off);
                    s2 += __shfl_xor(s2, off);
                }
                float mean = s * (1.0f / 64.0f);
                float var  = s2 * (1.0f / 64.0f) - mean * mean;
                float nv = (v - mean) * rsqrtf(var + 1e-5f);
                out[(size_t)b * (S_ * D_) + r * 64 + d] = nv * g + bb;
            }
        }
    }
}

extern "C" void kernel_launch(void* const* d_in, const int* in_sizes, int n_in,
                              void* d_out, int out_size, void* d_ws, size_t ws_size,
                              hipStream_t stream) {
    const float* x    = (const float*)d_in[0];
    const float* Wq   = (const float*)d_in[1];
    const float* bq   = (const float*)d_in[2];
    const float* Wk   = (const float*)d_in[3];
    const float* bk   = (const float*)d_in[4];
    const float* Wv   = (const float*)d_in[5];
    const float* bv   = (const float*)d_in[6];
    const float* Wo   = (const float*)d_in[7];
    const float* bo   = (const float*)d_in[8];
    const float* ln1g = (const float*)d_in[9];
    const float* ln1b = (const float*)d_in[10];
    const float* W1   = (const float*)d_in[11];
    const float* b1   = (const float*)d_in[12];
    const float* W2   = (const float*)d_in[13];
    const float* b2   = (const float*)d_in[14];
    const float* ln2g = (const float*)d_in[15];
    const float* ln2b = (const float*)d_in[16];
    float* out = (float*)d_out;
    float* pe  = (float*)d_ws;

    hipLaunchKernelGGL(pe_kernel, dim3((S_ * D_ + 255) / 256), dim3(256), 0, stream, pe);
    hipLaunchKernelGGL(encoder_kernel, dim3(NB), dim3(512), 0, stream,
                       x, Wq, bq, Wk, bk, Wv, bv, Wo, bo,
                       ln1g, ln1b, W1, b1, W2, b2, ln2g, ln2b, pe, out);
}

// Round 4
// 1062.623 us; speedup vs baseline: 9.1465x; 6.4161x over previous
//
#include <hip/hip_runtime.h>
#include <math.h>

#define NB 8192
#define S_ 45
#define D_ 64
#define FF_ 256
#define LD 68      // padded row stride for [45][64] LDS tiles
#define LDF 132    // padded row stride for FFN half-tile [45][128]

__global__ void pe_kernel(float* __restrict__ pe) {
    int idx = blockIdx.x * 256 + threadIdx.x;
    if (idx < S_ * D_) {
        int s = idx / D_, d = idx % D_;
        float div = expf(-logf(10000.0f) * (float)(d & ~1) / (float)D_);
        float ang = (float)s * div;
        pe[idx] = (d & 1) ? cosf(ang) : sinf(ang);
    }
}

__device__ inline float dot8(const float4 a1, const float4 a2,
                             const float4 b1, const float4 b2) {
    return a1.x * b1.x + a1.y * b1.y + a1.z * b1.z + a1.w * b1.w +
           a2.x * b2.x + a2.y * b2.y + a2.z * b2.z + a2.w * b2.w;
}

__device__ inline void fma4x4(float4& acc, const float4 hv,
                              const float4 w0, const float4 w1,
                              const float4 w2, const float4 w3) {
    acc.x += hv.x * w0.x + hv.y * w1.x + hv.z * w2.x + hv.w * w3.x;
    acc.y += hv.x * w0.y + hv.y * w1.y + hv.z * w2.y + hv.w * w3.y;
    acc.z += hv.x * w0.z + hv.y * w1.z + hv.z * w2.z + hv.w * w3.z;
    acc.w += hv.x * w0.w + hv.y * w1.w + hv.z * w2.w + hv.w * w3.w;
}

// Empirically this toolchain caps VGPR at ~256/min_waves: (512,2)->128 spilled
// ~9.5 GB of scratch each way. (512,1) -> cap 256; live-set peak ~110, so the
// allocator should land spill-free. 8 waves/CU occupancy, same as before.
__launch_bounds__(512, 1)
__global__ void encoder_kernel(
    const float* __restrict__ x,
    const float* __restrict__ Wq, const float* __restrict__ bq,
    const float* __restrict__ Wk, const float* __restrict__ bk,
    const float* __restrict__ Wv, const float* __restrict__ bv,
    const float* __restrict__ Wo, const float* __restrict__ bo,
    const float* __restrict__ ln1g, const float* __restrict__ ln1b,
    const float* __restrict__ W1, const float* __restrict__ b1,
    const float* __restrict__ W2, const float* __restrict__ b2,
    const float* __restrict__ ln2g, const float* __restrict__ ln2b,
    const float* __restrict__ pe,
    float* __restrict__ out)
{
    __shared__ float h[S_ * LD];
    __shared__ float U[3 * S_ * LD];
    float* qs = U;
    float* ks = U + S_ * LD;
    float* vs = U + 2 * S_ * LD;
    float* os = ks;   // o overlays k (k dead after attention pass B)
    float* fs = U;    // f overlays q+k (dead after LN1 / step 4)

    const int t = threadIdx.x;
    const int b = blockIdx.x;

    // ---- 1. h = x + pe ------------------------------------------------
    {
        const float4* x4 = (const float4*)(x + (size_t)b * (S_ * D_));
        const float4* p4 = (const float4*)pe;
        for (int idx = t; idx < S_ * D_ / 4; idx += 512) {
            int r = idx >> 4, c4 = (idx & 15) << 2;
            float4 a = x4[idx], p = p4[idx];
            *(float4*)&h[r * LD + c4] =
                make_float4(a.x + p.x, a.y + p.y, a.z + p.z, a.w + p.w);
        }
    }
    __syncthreads();

    // ---- 2. fused Q,K,V projections ----------------------------------
    {
        const int c = t & 63, rg = t >> 6;
        float aq[6], ak[6], av[6];
        #pragma unroll
        for (int i = 0; i < 6; ++i) { aq[i] = 0.f; ak[i] = 0.f; av[i] = 0.f; }
        #pragma unroll 2
        for (int k4 = 0; k4 < D_; k4 += 4) {
            float4 hv[6];
            #pragma unroll
            for (int i = 0; i < 6; ++i) {
                int r = rg + 8 * i;
                hv[i] = (r < S_) ? *(const float4*)&h[r * LD + k4]
                                 : make_float4(0.f, 0.f, 0.f, 0.f);
            }
            float wq0 = Wq[(k4 + 0) * 64 + c], wq1 = Wq[(k4 + 1) * 64 + c];
            float wq2 = Wq[(k4 + 2) * 64 + c], wq3 = Wq[(k4 + 3) * 64 + c];
            float wk0 = Wk[(k4 + 0) * 64 + c], wk1 = Wk[(k4 + 1) * 64 + c];
            float wk2 = Wk[(k4 + 2) * 64 + c], wk3 = Wk[(k4 + 3) * 64 + c];
            float wv0 = Wv[(k4 + 0) * 64 + c], wv1 = Wv[(k4 + 1) * 64 + c];
            float wv2 = Wv[(k4 + 2) * 64 + c], wv3 = Wv[(k4 + 3) * 64 + c];
            #pragma unroll
            for (int i = 0; i < 6; ++i) {
                aq[i] += hv[i].x * wq0 + hv[i].y * wq1 + hv[i].z * wq2 + hv[i].w * wq3;
                ak[i] += hv[i].x * wk0 + hv[i].y * wk1 + hv[i].z * wk2 + hv[i].w * wk3;
                av[i] += hv[i].x * wv0 + hv[i].y * wv1 + hv[i].z * wv2 + hv[i].w * wv3;
            }
        }
        float bqc = bq[c], bkc = bk[c], bvc = bv[c];
        #pragma unroll
        for (int i = 0; i < 6; ++i) {
            int r = rg + 8 * i;
            if (r < S_) {
                qs[r * LD + c] = aq[i] + bqc;
                ks[r * LD + c] = ak[i] + bkc;
                vs[r * LD + c] = av[i] + bvc;
            }
        }
    }
    __syncthreads();

    // ---- 3. attention: one (q-row, head) per thread, 2-pass -----------
    {
        int qr = 0, hd = 0;
        float4 o1 = make_float4(0.f, 0.f, 0.f, 0.f);
        float4 o2 = make_float4(0.f, 0.f, 0.f, 0.f);
        const bool act = (t < S_ * 8);
        if (act) {
            qr = t >> 3;
            hd = (t & 7) << 3;
            const float scale = 0.35355339059327373f;  // 1/sqrt(8)
            float4 qa = *(const float4*)&qs[qr * LD + hd];
            float4 qb = *(const float4*)&qs[qr * LD + hd + 4];
            float m = -3.0e38f;
            #pragma unroll 3
            for (int k = 0; k < S_; ++k) {
                float4 ka = *(const float4*)&ks[k * LD + hd];
                float4 kb = *(const float4*)&ks[k * LD + hd + 4];
                m = fmaxf(m, dot8(qa, qb, ka, kb));
            }
            float l = 0.f;
            #pragma unroll 3
            for (int k = 0; k < S_; ++k) {
                float4 ka = *(const float4*)&ks[k * LD + hd];
                float4 kb = *(const float4*)&ks[k * LD + hd + 4];
                float p = __expf((dot8(qa, qb, ka, kb) - m) * scale);
                l += p;
                float4 va = *(const float4*)&vs[k * LD + hd];
                float4 vb = *(const float4*)&vs[k * LD + hd + 4];
                o1.x += p * va.x; o1.y += p * va.y; o1.z += p * va.z; o1.w += p * va.w;
                o2.x += p * vb.x; o2.y += p * vb.y; o2.z += p * vb.z; o2.w += p * vb.w;
            }
            float inv = 1.0f / l;
            o1.x *= inv; o1.y *= inv; o1.z *= inv; o1.w *= inv;
            o2.x *= inv; o2.y *= inv; o2.z *= inv; o2.w *= inv;
        }
        __syncthreads();               // all reads of k done before o overlays it
        if (act) {
            *(float4*)&os[qr * LD + hd]     = o1;
            *(float4*)&os[qr * LD + hd + 4] = o2;
        }
    }
    __syncthreads();

    // ---- 4. t1 = o @ Wo + bo + h (residual) -> q-space ----------------
    {
        const int c0 = (t & 15) << 2, rg = t >> 4;
        float4 acc[2];
        acc[0] = make_float4(0.f, 0.f, 0.f, 0.f);
        acc[1] = make_float4(0.f, 0.f, 0.f, 0.f);
        #pragma unroll 2
        for (int k4 = 0; k4 < D_; k4 += 4) {
            float4 ov[2];
            #pragma unroll
            for (int i = 0; i < 2; ++i) {
                int r = rg + 32 * i;
                ov[i] = (r < S_) ? *(const float4*)&os[r * LD + k4]
                                 : make_float4(0.f, 0.f, 0.f, 0.f);
            }
            float4 w0 = *(const float4*)&Wo[(k4 + 0) * 64 + c0];
            float4 w1 = *(const float4*)&Wo[(k4 + 1) * 64 + c0];
            float4 w2 = *(const float4*)&Wo[(k4 + 2) * 64 + c0];
            float4 w3 = *(const float4*)&Wo[(k4 + 3) * 64 + c0];
            fma4x4(acc[0], ov[0], w0, w1, w2, w3);
            fma4x4(acc[1], ov[1], w0, w1, w2, w3);
        }
        float4 bo4 = *(const float4*)&bo[c0];
        #pragma unroll
        for (int i = 0; i < 2; ++i) {
            int r = rg + 32 * i;
            if (r < S_) {
                float4 hr = *(const float4*)&h[r * LD + c0];
                float4 o;
                o.x = acc[i].x + bo4.x + hr.x;
                o.y = acc[i].y + bo4.y + hr.y;
                o.z = acc[i].z + bo4.z + hr.z;
                o.w = acc[i].w + bo4.w + hr.w;
                *(float4*)&qs[r * LD + c0] = o;
            }
        }
    }
    __syncthreads();

    // ---- 5. LN1: t1 (q-space) -> h2 (h-space) -------------------------
    {
        const int wv = t >> 6, d = t & 63;
        const float g = ln1g[d], bb = ln1b[d];
        for (int i = 0; i < 6; ++i) {
            int r = wv + 8 * i;
            if (r < S_) {
                float v = qs[r * LD + d];
                float s = v, s2 = v * v;
                #pragma unroll
                for (int off = 32; off; off >>= 1) {
                    s  += __shfl_xor(s, off);
                    s2 += __shfl_xor(s2, off);
                }
                float mean = s * (1.0f / 64.0f);
                float var  = s2 * (1.0f / 64.0f) - mean * mean;
                float nv = (v - mean) * rsqrtf(var + 1e-5f);
                h[r * LD + d] = nv * g + bb;
            }
        }
    }
    __syncthreads();

    // ---- 6+7. FFN in two 128-wide halves; FFN2 accumulates in regs ----
    const int f_c0 = (t & 31) << 2, f_rg = t >> 5;
    const int g_c0 = (t & 15) << 2, g_rg = t >> 4;
    float4 facc[2];
    facc[0] = make_float4(0.f, 0.f, 0.f, 0.f);
    facc[1] = make_float4(0.f, 0.f, 0.f, 0.f);
    for (int half = 0; half < 2; ++half) {
        // FFN1: f = relu(h2 @ W1[:, half*128 ..] + b1)
        {
            float4 a1[3];
            #pragma unroll
            for (int i = 0; i < 3; ++i) a1[i] = make_float4(0.f, 0.f, 0.f, 0.f);
            #pragma unroll 2
            for (int k4 = 0; k4 < D_; k4 += 4) {
                float4 hv[3];
                #pragma unroll
                for (int i = 0; i < 3; ++i) {
                    int r = f_rg + 16 * i;
                    hv[i] = (r < S_) ? *(const float4*)&h[r * LD + k4]
                                     : make_float4(0.f, 0.f, 0.f, 0.f);
                }
                float4 w0 = *(const float4*)&W1[(k4 + 0) * FF_ + half * 128 + f_c0];
                float4 w1 = *(const float4*)&W1[(k4 + 1) * FF_ + half * 128 + f_c0];
                float4 w2 = *(const float4*)&W1[(k4 + 2) * FF_ + half * 128 + f_c0];
                float4 w3 = *(const float4*)&W1[(k4 + 3) * FF_ + half * 128 + f_c0];
                fma4x4(a1[0], hv[0], w0, w1, w2, w3);
                fma4x4(a1[1], hv[1], w0, w1, w2, w3);
                fma4x4(a1[2], hv[2], w0, w1, w2, w3);
            }
            float4 bias = *(const float4*)&b1[half * 128 + f_c0];
            #pragma unroll
            for (int i = 0; i < 3; ++i) {
                int r = f_rg + 16 * i;
                if (r < S_) {
                    float4 o;
                    o.x = fmaxf(a1[i].x + bias.x, 0.f);
                    o.y = fmaxf(a1[i].y + bias.y, 0.f);
                    o.z = fmaxf(a1[i].z + bias.z, 0.f);
                    o.w = fmaxf(a1[i].w + bias.w, 0.f);
                    *(float4*)&fs[r * LDF + f_c0] = o;
                }
            }
        }
        __syncthreads();
        // FFN2 partial: facc += f @ W2[half*128 .., :]
        {
            #pragma unroll 2
            for (int k4 = 0; k4 < 128; k4 += 4) {
                float4 fv[2];
                #pragma unroll
                for (int i = 0; i < 2; ++i) {
                    int r = g_rg + 32 * i;
                    fv[i] = (r < S_) ? *(const float4*)&fs[r * LDF + k4]
                                     : make_float4(0.f, 0.f, 0.f, 0.f);
                }
                float4 w0 = *(const float4*)&W2[(half * 128 + k4 + 0) * 64 + g_c0];
                float4 w1 = *(const float4*)&W2[(half * 128 + k4 + 1) * 64 + g_c0];
                float4 w2 = *(const float4*)&W2[(half * 128 + k4 + 2) * 64 + g_c0];
                float4 w3 = *(const float4*)&W2[(half * 128 + k4 + 3) * 64 + g_c0];
                fma4x4(facc[0], fv[0], w0, w1, w2, w3);
                fma4x4(facc[1], fv[1], w0, w1, w2, w3);
            }
        }
        __syncthreads();   // before next half overwrites fs
    }
    // FFN2 epilogue: t2 = facc + b2 + h2 -> h-space
    {
        float4 b24 = *(const float4*)&b2[g_c0];
        #pragma unroll
        for (int i = 0; i < 2; ++i) {
            int r = g_rg + 32 * i;
            if (r < S_) {
                float4 hr = *(const float4*)&h[r * LD + g_c0];
                float4 o;
                o.x = facc[i].x + b24.x + hr.x;
                o.y = facc[i].y + b24.y + hr.y;
                o.z = facc[i].z + b24.z + hr.z;
                o.w = facc[i].w + b24.w + hr.w;
                *(float4*)&h[r * LD + g_c0] = o;
            }
        }
    }
    __syncthreads();

    // ---- 8. LN2: t2 (h-space) -> out ----------------------------------
    {
        const int wv = t >> 6, d = t & 63;
        const float g = ln2g[d], bb = ln2b[d];
        for (int i = 0; i < 6; ++i) {
            int r = wv + 8 * i;
            if (r < S_) {
                float v = h[r * LD + d];
                float s = v, s2 = v * v;
                #pragma unroll
                for (int off = 32; off; off >>= 1) {
                    s  += __shfl_xor(s, off);
                    s2 += __shfl_xor(s2, off);
                }
                float mean = s * (1.0f / 64.0f);
                float var  = s2 * (1.0f / 64.0f) - mean * mean;
                float nv = (v - mean) * rsqrtf(var + 1e-5f);
                out[(size_t)b * (S_ * D_) + r * 64 + d] = nv * g + bb;
            }
        }
    }
}

extern "C" void kernel_launch(void* const* d_in, const int* in_sizes, int n_in,
                              void* d_out, int out_size, void* d_ws, size_t ws_size,
                              hipStream_t stream) {
    const float* x    = (const float*)d_in[0];
    const float* Wq   = (const float*)d_in[1];
    const float* bq   = (const float*)d_in[2];
    const float* Wk   = (const float*)d_in[3];
    const float* bk   = (const float*)d_in[4];
    const float* Wv   = (const float*)d_in[5];
    const float* bv   = (const float*)d_in[6];
    const float* Wo   = (const float*)d_in[7];
    const float* bo   = (const float*)d_in[8];
    const float* ln1g = (const float*)d_in[9];
    const float* ln1b = (const float*)d_in[10];
    const float* W1   = (const float*)d_in[11];
    const float* b1   = (const float*)d_in[12];
    const float* W2   = (const float*)d_in[13];
    const float* b2   = (const float*)d_in[14];
    const float* ln2g = (const float*)d_in[15];
    const float* ln2b = (const float*)d_in[16];
    float* out = (float*)d_out;
    float* pe  = (float*)d_ws;

    hipLaunchKernelGGL(pe_kernel, dim3((S_ * D_ + 255) / 256), dim3(256), 0, stream, pe);
    hipLaunchKernelGGL(encoder_kernel, dim3(NB), dim3(512), 0, stream,
                       x, Wq, bq, Wk, bk, Wv, bv, Wo, bo,
                       ln1g, ln1b, W1, b1, W2, b2, ln2g, ln2b, pe, out);
}

// Round 5
// 433.794 us; speedup vs baseline: 22.4053x; 2.4496x over previous
//
#include <hip/hip_runtime.h>
#include <math.h>

#define NB 8192
#define S_ 45
#define D_ 64
#define FF_ 256
#define LDH 68     // f32 row stride for hf/t1
#define HBS 72     // bf16 row stride for h/q/k/v/o tiles (144 B, 16B-aligned)
#define FBS 272    // bf16 row stride for FFN inner tile (544 B, 16B-aligned)

typedef __attribute__((ext_vector_type(4))) float f32x4;
typedef __attribute__((ext_vector_type(8))) short s16x8;
typedef __attribute__((ext_vector_type(4))) short s16x4;

// ws layout (bytes): pe f32 [45*64] @0 ; WqkvT bf16 [192][64] @11520 ;
// WoT bf16 [64][64] @36096 ; W1T bf16 [256][64] @44288 ; W2T bf16 [64][256] @77056
#define WS_QKV 11520
#define WS_WO  36096
#define WS_W1  44288
#define WS_W2  77056

__device__ inline short f2bf(float f) {   // RNE float->bf16 bits
    union { float f; unsigned u; } c; c.f = f;
    unsigned u = c.u;
    return (short)((u + 0x7FFFu + ((u >> 16) & 1u)) >> 16);
}
__device__ inline void bf8_to_f(const s16x8 v, float* o) {
    #pragma unroll
    for (int i = 0; i < 8; ++i) {
        union { unsigned u; float f; } c;
        c.u = ((unsigned)(unsigned short)v[i]) << 16;
        o[i] = c.f;
    }
}

__global__ void prep_kernel(const float* __restrict__ Wq, const float* __restrict__ Wk,
                            const float* __restrict__ Wv, const float* __restrict__ Wo,
                            const float* __restrict__ W1, const float* __restrict__ W2,
                            void* __restrict__ ws) {
    float* pe   = (float*)ws;
    short* wqkv = (short*)((char*)ws + WS_QKV);
    short* wo   = (short*)((char*)ws + WS_WO);
    short* w1   = (short*)((char*)ws + WS_W1);
    short* w2   = (short*)((char*)ws + WS_W2);
    int i = blockIdx.x * 256 + threadIdx.x;
    if (i < S_ * D_) {                       // positional encoding (f32)
        int s = i / D_, d = i % D_;
        float div = expf(-logf(10000.0f) * (float)(d & ~1) / (float)D_);
        float ang = (float)s * div;
        pe[i] = (d & 1) ? cosf(ang) : sinf(ang);
    }
    if (i < 12288) {                         // WqkvT[n][k] = W{q,k,v}[k][n&63]
        int n = i >> 6, k = i & 63;
        const float* W = (n < 64) ? Wq : (n < 128 ? Wk : Wv);
        wqkv[i] = f2bf(W[k * 64 + (n & 63)]);
    }
    if (i < 4096) {                          // WoT[n][k] = Wo[k][n]
        int n = i >> 6, k = i & 63;
        wo[i] = f2bf(Wo[k * 64 + n]);
    }
    if (i < 16384) {                         // W1T[n][k] = W1[k][n], n<256,k<64
        int n = i >> 6, k = i & 63;
        w1[i] = f2bf(W1[k * FF_ + n]);
        // W2T[n][k] = W2[k][n], n<64,k<256
        int n2 = i >> 8, k2 = i & 255;
        w2[i] = f2bf(W2[k2 * 64 + n2]);
    }
}

__launch_bounds__(512, 1)
__global__ void encoder_kernel(
    const float* __restrict__ x,
    const float* __restrict__ bq, const float* __restrict__ bk,
    const float* __restrict__ bv, const float* __restrict__ bo,
    const float* __restrict__ ln1g, const float* __restrict__ ln1b,
    const float* __restrict__ b1, const float* __restrict__ b2,
    const float* __restrict__ ln2g, const float* __restrict__ ln2b,
    const void* __restrict__ ws,
    float* __restrict__ out)
{
    const float* pe    = (const float*)ws;
    const short* wqkvT = (const short*)((const char*)ws + WS_QKV);
    const short* woT   = (const short*)((const char*)ws + WS_WO);
    const short* w1T   = (const short*)((const char*)ws + WS_W1);
    const short* w2T   = (const short*)((const char*)ws + WS_W2);

    // LDS: hf (fp32 residual / h2 / t2), hb (bf16 A-operand h / h2),
    //      un = union{ q|k|v bf16 ; o bf16 over q ; t1 f32 over k|v ; f bf16 }
    __shared__ __align__(16) float hf[S_ * LDH];        // 12240 B
    __shared__ __align__(16) short hb[48 * HBS];        //  6912 B
    __shared__ __align__(16) short un[48 * FBS];        // 26112 B
    short* qb = un;
    short* kb = un + 48 * HBS;
    short* vb = un + 2 * 48 * HBS;
    short* ob = un;                                     // o over q (after barrier)
    float* t1 = (float*)(un + 48 * HBS);                // 12240 B over k|v (13824 B)
    short* fb = un;                                     // FFN inner [48][FBS]

    const int t = threadIdx.x;
    const int b = blockIdx.x;
    const int w = t >> 6, l = t & 63;
    const int lr = l & 15, lg = l >> 4;   // MFMA frag: row/col-in-tile, k/row-group

    // ---- 1. h = x + pe -> hf (f32) + hb (bf16) -------------------------
    {
        const float4* x4 = (const float4*)(x + (size_t)b * (S_ * D_));
        const float4* p4 = (const float4*)pe;
        for (int i = t; i < S_ * D_ / 4; i += 512) {
            int r = i >> 4, c4 = (i & 15) << 2;
            float4 a = x4[i], p = p4[i];
            float4 hv = make_float4(a.x + p.x, a.y + p.y, a.z + p.z, a.w + p.w);
            *(float4*)&hf[r * LDH + c4] = hv;
            s16x4 hv16 = { f2bf(hv.x), f2bf(hv.y), f2bf(hv.z), f2bf(hv.w) };
            *(s16x4*)&hb[r * HBS + c4] = hv16;
        }
    }
    __syncthreads();

    // ---- 2. fused QKV via MFMA: [48x192] = hb @ WqkvT^T ---------------
    {
        for (int id = w; id < 36; id += 8) {
            const int m0 = (id % 3) << 4, n0 = (id / 3) << 4;
            f32x4 acc = {0.f, 0.f, 0.f, 0.f};
            #pragma unroll
            for (int k0 = 0; k0 < 64; k0 += 32) {
                s16x8 af = *(const s16x8*)&hb[(m0 + lr) * HBS + k0 + lg * 8];
                s16x8 bf = *(const s16x8*)&wqkvT[(n0 + lr) * 64 + k0 + lg * 8];
                acc = __builtin_amdgcn_mfma_f32_16x16x32_bf16(af, bf, acc, 0, 0, 0);
            }
            const int col = n0 + lr;
            float bias; short* dst; int cc;
            if (col < 64)       { bias = bq[col];       dst = qb; cc = col; }
            else if (col < 128) { bias = bk[col - 64];  dst = kb; cc = col - 64; }
            else                { bias = bv[col - 128]; dst = vb; cc = col - 128; }
            #pragma unroll
            for (int r = 0; r < 4; ++r) {
                int row = m0 + lg * 4 + r;
                if (row < S_) dst[row * HBS + cc] = f2bf(acc[r] + bias);
            }
        }
    }
    __syncthreads();

    // ---- 3. attention (fp32 VALU on bf16 q,k,v), 2-pass ---------------
    {
        float o1[8];
        int qr = 0, hd = 0;
        const bool act = (t < S_ * 8);
        if (act) {
            qr = t >> 3;
            hd = (t & 7) << 3;
            const float scale = 0.35355339059327373f;  // 1/sqrt(8)
            float qv[8];
            bf8_to_f(*(const s16x8*)&qb[qr * HBS + hd], qv);
            float m = -3.0e38f;
            #pragma unroll 3
            for (int k = 0; k < S_; ++k) {
                float kv[8];
                bf8_to_f(*(const s16x8*)&kb[k * HBS + hd], kv);
                float d = 0.f;
                #pragma unroll
                for (int j = 0; j < 8; ++j) d += qv[j] * kv[j];
                m = fmaxf(m, d);
            }
            #pragma unroll
            for (int j = 0; j < 8; ++j) o1[j] = 0.f;
            float lsum = 0.f;
            #pragma unroll 3
            for (int k = 0; k < S_; ++k) {
                float kv[8], vv[8];
                bf8_to_f(*(const s16x8*)&kb[k * HBS + hd], kv);
                bf8_to_f(*(const s16x8*)&vb[k * HBS + hd], vv);
                float d = 0.f;
                #pragma unroll
                for (int j = 0; j < 8; ++j) d += qv[j] * kv[j];
                float p = __expf((d - m) * scale);
                lsum += p;
                #pragma unroll
                for (int j = 0; j < 8; ++j) o1[j] += p * vv[j];
            }
            float inv = 1.0f / lsum;
            #pragma unroll
            for (int j = 0; j < 8; ++j) o1[j] *= inv;
        }
        __syncthreads();               // all q reads done before o overlays q
        if (act) {
            #pragma unroll
            for (int j = 0; j < 8; ++j) ob[qr * HBS + hd + j] = f2bf(o1[j]);
        }
    }
    __syncthreads();

    // ---- 4. t1 = o @ Wo + bo + h (residual), MFMA -> t1 (f32) ---------
    {
        for (int id = w; id < 12; id += 8) {
            const int m0 = (id % 3) << 4, n0 = (id / 3) << 4;
            f32x4 acc = {0.f, 0.f, 0.f, 0.f};
            #pragma unroll
            for (int k0 = 0; k0 < 64; k0 += 32) {
                s16x8 af = *(const s16x8*)&ob[(m0 + lr) * HBS + k0 + lg * 8];
                s16x8 bf = *(const s16x8*)&woT[(n0 + lr) * 64 + k0 + lg * 8];
                acc = __builtin_amdgcn_mfma_f32_16x16x32_bf16(af, bf, acc, 0, 0, 0);
            }
            const int col = n0 + lr;
            const float bias = bo[col];
            #pragma unroll
            for (int r = 0; r < 4; ++r) {
                int row = m0 + lg * 4 + r;
                if (row < S_)
                    t1[row * LDH + col] = acc[r] + bias + hf[row * LDH + col];
            }
        }
    }
    __syncthreads();

    // ---- 5. LN1: t1 -> h2 (hf f32 + hb bf16) --------------------------
    {
        const int wv = t >> 6, d = t & 63;
        const float g = ln1g[d], bb = ln1b[d];
        for (int i = 0; i < 6; ++i) {
            int r = wv + 8 * i;
            if (r < S_) {
                float v = t1[r * LDH + d];
                float s = v, s2 = v * v;
                #pragma unroll
                for (int off = 32; off; off >>= 1) {
                    s  += __shfl_xor(s, off);
                    s2 += __shfl_xor(s2, off);
                }
                float mean = s * (1.0f / 64.0f);
                float var  = s2 * (1.0f / 64.0f) - mean * mean;
                float nv = (v - mean) * rsqrtf(var + 1e-5f);
                float res = nv * g + bb;
                hf[r * LDH + d] = res;
                hb[r * HBS + d] = f2bf(res);
            }
        }
    }
    __syncthreads();

    // ---- 6. FFN1 via MFMA: f = relu(h2 @ W1 + b1) -> fb (bf16) --------
    {
        for (int id = w; id < 48; id += 8) {
            const int m0 = (id % 3) << 4, n0 = (id / 3) << 4;
            f32x4 acc = {0.f, 0.f, 0.f, 0.f};
            #pragma unroll
            for (int k0 = 0; k0 < 64; k0 += 32) {
                s16x8 af = *(const s16x8*)&hb[(m0 + lr) * HBS + k0 + lg * 8];
                s16x8 bf = *(const s16x8*)&w1T[(n0 + lr) * 64 + k0 + lg * 8];
                acc = __builtin_amdgcn_mfma_f32_16x16x32_bf16(af, bf, acc, 0, 0, 0);
            }
            const int col = n0 + lr;
            const float bias = b1[col];
            #pragma unroll
            for (int r = 0; r < 4; ++r) {
                int row = m0 + lg * 4 + r;
                if (row < S_)
                    fb[row * FBS + col] = f2bf(fmaxf(acc[r] + bias, 0.f));
            }
        }
    }
    __syncthreads();

    // ---- 7. FFN2 via MFMA: t2 = f @ W2 + b2 + h2 -> hf (in place) -----
    {
        for (int id = w; id < 12; id += 8) {
            const int m0 = (id % 3) << 4, n0 = (id / 3) << 4;
            f32x4 acc = {0.f, 0.f, 0.f, 0.f};
            #pragma unroll 4
            for (int k0 = 0; k0 < FF_; k0 += 32) {
                s16x8 af = *(const s16x8*)&fb[(m0 + lr) * FBS + k0 + lg * 8];
                s16x8 bf = *(const s16x8*)&w2T[(n0 + lr) * 256 + k0 + lg * 8];
                acc = __builtin_amdgcn_mfma_f32_16x16x32_bf16(af, bf, acc, 0, 0, 0);
            }
            const int col = n0 + lr;
            const float bias = b2[col];
            #pragma unroll
            for (int r = 0; r < 4; ++r) {
                int row = m0 + lg * 4 + r;
                if (row < S_) {
                    int o = row * LDH + col;
                    hf[o] = acc[r] + bias + hf[o];
                }
            }
        }
    }
    __syncthreads();

    // ---- 8. LN2: hf -> out --------------------------------------------
    {
        const int wv = t >> 6, d = t & 63;
        const float g = ln2g[d], bb = ln2b[d];
        for (int i = 0; i < 6; ++i) {
            int r = wv + 8 * i;
            if (r < S_) {
                float v = hf[r * LDH + d];
                float s = v, s2 = v * v;
                #pragma unroll
                for (int off = 32; off; off >>= 1) {
                    s  += __shfl_xor(s, off);
                    s2 += __shfl_xor(s2, off);
                }
                float mean = s * (1.0f / 64.0f);
                float var  = s2 * (1.0f / 64.0f) - mean * mean;
                float nv = (v - mean) * rsqrtf(var + 1e-5f);
                out[(size_t)b * (S_ * D_) + r * 64 + d] = nv * g + bb;
            }
        }
    }
}

extern "C" void kernel_launch(void* const* d_in, const int* in_sizes, int n_in,
                              void* d_out, int out_size, void* d_ws, size_t ws_size,
                              hipStream_t stream) {
    const float* x    = (const float*)d_in[0];
    const float* Wq   = (const float*)d_in[1];
    const float* bq   = (const float*)d_in[2];
    const float* Wk   = (const float*)d_in[3];
    const float* bk   = (const float*)d_in[4];
    const float* Wv   = (const float*)d_in[5];
    const float* bv   = (const float*)d_in[6];
    const float* Wo   = (const float*)d_in[7];
    const float* bo   = (const float*)d_in[8];
    const float* ln1g = (const float*)d_in[9];
    const float* ln1b = (const float*)d_in[10];
    const float* W1   = (const float*)d_in[11];
    const float* b1   = (const float*)d_in[12];
    const float* W2   = (const float*)d_in[13];
    const float* b2   = (const float*)d_in[14];
    const float* ln2g = (const float*)d_in[15];
    const float* ln2b = (const float*)d_in[16];
    float* out = (float*)d_out;

    hipLaunchKernelGGL(prep_kernel, dim3(64), dim3(256), 0, stream,
                       Wq, Wk, Wv, Wo, W1, W2, d_ws);
    hipLaunchKernelGGL(encoder_kernel, dim3(NB), dim3(512), 0, stream,
                       x, bq, bk, bv, bo, ln1g, ln1b, b1, b2, ln2g, ln2b,
                       d_ws, out);
}

// Round 6
// 376.465 us; speedup vs baseline: 25.8172x; 1.1523x over previous
//
#include <hip/hip_runtime.h>
#include <math.h>

#define NB 8192
#define S_ 45
#define D_ 64
#define FF_ 256
#define LDH 68     // f32 row stride for hf/t1 (68 dwords: 2-way-free on tiled reads)
#define HBS 72     // bf16 row stride for hb/ob (144 B, 16B-aligned, 2-way-free)
#define FBS 280    // bf16 row stride for FFN inner tile (560 B; 140 dwords = 2-way-free)

typedef __attribute__((ext_vector_type(4))) float f32x4;
typedef __attribute__((ext_vector_type(8))) short s16x8;
typedef __attribute__((ext_vector_type(4))) short s16x4;

// ws layout (bytes): pe f32 [45*64] @0 ; WqkvT bf16 [192][64] @11520 ;
// WoT bf16 [64][64] @36096 ; W1T bf16 [256][64] @44288 ; W2T bf16 [64][256] @77056
#define WS_QKV 11520
#define WS_WO  36096
#define WS_W1  44288
#define WS_W2  77056

__device__ inline short f2bf(float f) {   // RNE float->bf16 bits
    union { float f; unsigned u; } c; c.f = f;
    unsigned u = c.u;
    return (short)((u + 0x7FFFu + ((u >> 16) & 1u)) >> 16);
}

__global__ void prep_kernel(const float* __restrict__ Wq, const float* __restrict__ Wk,
                            const float* __restrict__ Wv, const float* __restrict__ Wo,
                            const float* __restrict__ W1, const float* __restrict__ W2,
                            void* __restrict__ ws) {
    float* pe   = (float*)ws;
    short* wqkv = (short*)((char*)ws + WS_QKV);
    short* wo   = (short*)((char*)ws + WS_WO);
    short* w1   = (short*)((char*)ws + WS_W1);
    short* w2   = (short*)((char*)ws + WS_W2);
    int i = blockIdx.x * 256 + threadIdx.x;
    if (i < S_ * D_) {                       // positional encoding (f32)
        int s = i / D_, d = i % D_;
        float div = expf(-logf(10000.0f) * (float)(d & ~1) / (float)D_);
        float ang = (float)s * div;
        pe[i] = (d & 1) ? cosf(ang) : sinf(ang);
    }
    if (i < 12288) {                         // WqkvT[n][k] = W{q,k,v}[k][n&63]
        int n = i >> 6, k = i & 63;
        const float* W = (n < 64) ? Wq : (n < 128 ? Wk : Wv);
        wqkv[i] = f2bf(W[k * 64 + (n & 63)]);
    }
    if (i < 4096) {                          // WoT[n][k] = Wo[k][n]
        int n = i >> 6, k = i & 63;
        wo[i] = f2bf(Wo[k * 64 + n]);
    }
    if (i < 16384) {                         // W1T[n][k] = W1[k][n], n<256,k<64
        int n = i >> 6, k = i & 63;
        w1[i] = f2bf(W1[k * FF_ + n]);
        // W2T[n][k] = W2[k][n], n<64,k<256
        int n2 = i >> 8, k2 = i & 255;
        w2[i] = f2bf(W2[k2 * 64 + n2]);
    }
}

__launch_bounds__(512, 1)
__global__ void encoder_kernel(
    const float* __restrict__ x,
    const float* __restrict__ bq, const float* __restrict__ bk,
    const float* __restrict__ bv, const float* __restrict__ bo,
    const float* __restrict__ ln1g, const float* __restrict__ ln1b,
    const float* __restrict__ b1, const float* __restrict__ b2,
    const float* __restrict__ ln2g, const float* __restrict__ ln2b,
    const void* __restrict__ ws,
    float* __restrict__ out)
{
    const float* pe    = (const float*)ws;
    const short* wqkvT = (const short*)((const char*)ws + WS_QKV);
    const short* woT   = (const short*)((const char*)ws + WS_WO);
    const short* w1T   = (const short*)((const char*)ws + WS_W1);
    const short* w2T   = (const short*)((const char*)ws + WS_W2);

    // LDS 53.7 KB total -> 3 blocks/CU:
    //  hf  f32 [45][68]  : residual h -> h2 -> t2
    //  hb bf16 [48][72]  : MFMA A-operand (h, then h2)
    //  un (34560 B union):
    //    phase attn: qf|kf|vf f32 [45][64] each (VALU attention, zero cvt)
    //    phase Wo  : ob bf16 [48][72] @0 ; t1 f32 [45][68] @+11520B
    //    phase FFN : fb bf16 [48][280]
    __shared__ __align__(16) float hf[S_ * LDH];
    __shared__ __align__(16) short hb[48 * HBS];
    __shared__ __align__(16) float un[8640];
    float* qf = un;
    float* kf = un + 2880;
    float* vf = un + 5760;
    short* ob = (short*)un;
    float* t1 = un + 2880;
    short* fb = (short*)un;

    const int t = threadIdx.x;
    const int b = blockIdx.x;
    const int w = t >> 6, l = t & 63;
    const int lr = l & 15, lg = l >> 4;   // MFMA frag coords

    // ---- 1. h = x + pe -> hf (f32) + hb (bf16) -------------------------
    {
        const float4* x4 = (const float4*)(x + (size_t)b * (S_ * D_));
        const float4* p4 = (const float4*)pe;
        for (int i = t; i < S_ * D_ / 4; i += 512) {
            int r = i >> 4, c4 = (i & 15) << 2;
            float4 a = x4[i], p = p4[i];
            float4 hv = make_float4(a.x + p.x, a.y + p.y, a.z + p.z, a.w + p.w);
            *(float4*)&hf[r * LDH + c4] = hv;
            s16x4 hv16 = { f2bf(hv.x), f2bf(hv.y), f2bf(hv.z), f2bf(hv.w) };
            *(s16x4*)&hb[r * HBS + c4] = hv16;
        }
    }
    __syncthreads();

    // ---- 2. fused QKV via MFMA: q->qf(f32), k->kf(f32), v->vf(f32) ----
    {
        for (int id = w; id < 36; id += 8) {
            const int m0 = (id % 3) << 4, n0 = (id / 3) << 4;
            f32x4 acc = {0.f, 0.f, 0.f, 0.f};
            #pragma unroll
            for (int k0 = 0; k0 < 64; k0 += 32) {
                s16x8 af = *(const s16x8*)&hb[(m0 + lr) * HBS + k0 + lg * 8];
                s16x8 bf = *(const s16x8*)&wqkvT[(n0 + lr) * 64 + k0 + lg * 8];
                acc = __builtin_amdgcn_mfma_f32_16x16x32_bf16(af, bf, acc, 0, 0, 0);
            }
            const int col = n0 + lr;
            float bias; float* dst; int cc;
            if (col < 64)       { bias = bq[col];       dst = qf; cc = col; }
            else if (col < 128) { bias = bk[col - 64];  dst = kf; cc = col - 64; }
            else                { bias = bv[col - 128]; dst = vf; cc = col - 128; }
            #pragma unroll
            for (int r = 0; r < 4; ++r) {
                int row = m0 + lg * 4 + r;
                if (row < S_) dst[row * 64 + cc] = acc[r] + bias;
            }
        }
    }
    __syncthreads();

    // ---- 3. attention: single pass, no max subtraction, pure f32 ------
    // scores*scale ~ N(0,1); exp2 arg bounded far below f32 overflow.
    {
        float o1[8];
        float4 ov16a, ov16b; (void)ov16a; (void)ov16b;
        int qr = 0, hd = 0;
        const bool act = (t < S_ * 8);
        if (act) {
            qr = t >> 3;
            hd = (t & 7) << 3;
            const float sc2 = 0.35355339059327373f * 1.44269504088896340f; // /sqrt(8)*log2e
            float4 q1 = *(const float4*)&qf[qr * 64 + hd];
            float4 q2 = *(const float4*)&qf[qr * 64 + hd + 4];
            #pragma unroll
            for (int j = 0; j < 8; ++j) o1[j] = 0.f;
            float lsum = 0.f;
            #pragma unroll 3
            for (int k = 0; k < S_; ++k) {
                float4 k1 = *(const float4*)&kf[k * 64 + hd];
                float4 k2 = *(const float4*)&kf[k * 64 + hd + 4];
                float d = q1.x * k1.x + q1.y * k1.y + q1.z * k1.z + q1.w * k1.w +
                          q2.x * k2.x + q2.y * k2.y + q2.z * k2.z + q2.w * k2.w;
                float p = __builtin_amdgcn_exp2f(d * sc2);
                lsum += p;
                float4 v1 = *(const float4*)&vf[k * 64 + hd];
                float4 v2 = *(const float4*)&vf[k * 64 + hd + 4];
                o1[0] += p * v1.x; o1[1] += p * v1.y; o1[2] += p * v1.z; o1[3] += p * v1.w;
                o1[4] += p * v2.x; o1[5] += p * v2.y; o1[6] += p * v2.z; o1[7] += p * v2.w;
            }
            float inv = 1.0f / lsum;
            #pragma unroll
            for (int j = 0; j < 8; ++j) o1[j] *= inv;
        }
        __syncthreads();               // all qf/kf/vf reads done before ob overlays
        if (act) {
            s16x8 o16 = { f2bf(o1[0]), f2bf(o1[1]), f2bf(o1[2]), f2bf(o1[3]),
                          f2bf(o1[4]), f2bf(o1[5]), f2bf(o1[6]), f2bf(o1[7]) };
            *(s16x8*)&ob[qr * HBS + hd] = o16;
        }
    }
    __syncthreads();

    // ---- 4. t1 = o @ Wo + bo + h (residual), MFMA -> t1 (f32) ---------
    {
        for (int id = w; id < 12; id += 8) {
            const int m0 = (id % 3) << 4, n0 = (id / 3) << 4;
            f32x4 acc = {0.f, 0.f, 0.f, 0.f};
            #pragma unroll
            for (int k0 = 0; k0 < 64; k0 += 32) {
                s16x8 af = *(const s16x8*)&ob[(m0 + lr) * HBS + k0 + lg * 8];
                s16x8 bf = *(const s16x8*)&woT[(n0 + lr) * 64 + k0 + lg * 8];
                acc = __builtin_amdgcn_mfma_f32_16x16x32_bf16(af, bf, acc, 0, 0, 0);
            }
            const int col = n0 + lr;
            const float bias = bo[col];
            #pragma unroll
            for (int r = 0; r < 4; ++r) {
                int row = m0 + lg * 4 + r;
                if (row < S_)
                    t1[row * LDH + col] = acc[r] + bias + hf[row * LDH + col];
            }
        }
    }
    __syncthreads();

    // ---- 5. LN1: t1 -> h2 (hf f32 + hb bf16) --------------------------
    {
        const int wv = t >> 6, d = t & 63;
        const float g = ln1g[d], bb = ln1b[d];
        for (int i = 0; i < 6; ++i) {
            int r = wv + 8 * i;
            if (r < S_) {
                float v = t1[r * LDH + d];
                float s = v, s2 = v * v;
                #pragma unroll
                for (int off = 32; off; off >>= 1) {
                    s  += __shfl_xor(s, off);
                    s2 += __shfl_xor(s2, off);
                }
                float mean = s * (1.0f / 64.0f);
                float var  = s2 * (1.0f / 64.0f) - mean * mean;
                float nv = (v - mean) * rsqrtf(var + 1e-5f);
                float res = nv * g + bb;
                hf[r * LDH + d] = res;
                hb[r * HBS + d] = f2bf(res);
            }
        }
    }
    __syncthreads();

    // ---- 6. FFN1 via MFMA: f = relu(h2 @ W1 + b1) -> fb (bf16) --------
    {
        for (int id = w; id < 48; id += 8) {
            const int m0 = (id % 3) << 4, n0 = (id / 3) << 4;
            f32x4 acc = {0.f, 0.f, 0.f, 0.f};
            #pragma unroll
            for (int k0 = 0; k0 < 64; k0 += 32) {
                s16x8 af = *(const s16x8*)&hb[(m0 + lr) * HBS + k0 + lg * 8];
                s16x8 bf = *(const s16x8*)&w1T[(n0 + lr) * 64 + k0 + lg * 8];
                acc = __builtin_amdgcn_mfma_f32_16x16x32_bf16(af, bf, acc, 0, 0, 0);
            }
            const int col = n0 + lr;
            const float bias = b1[col];
            #pragma unroll
            for (int r = 0; r < 4; ++r) {
                int row = m0 + lg * 4 + r;
                if (row < S_)
                    fb[row * FBS + col] = f2bf(fmaxf(acc[r] + bias, 0.f));
            }
        }
    }
    __syncthreads();

    // ---- 7. FFN2 via MFMA: t2 = f @ W2 + b2 + h2 -> hf (in place) -----
    {
        for (int id = w; id < 12; id += 8) {
            const int m0 = (id % 3) << 4, n0 = (id / 3) << 4;
            f32x4 acc = {0.f, 0.f, 0.f, 0.f};
            #pragma unroll 4
            for (int k0 = 0; k0 < FF_; k0 += 32) {
                s16x8 af = *(const s16x8*)&fb[(m0 + lr) * FBS + k0 + lg * 8];
                s16x8 bf = *(const s16x8*)&w2T[(n0 + lr) * 256 + k0 + lg * 8];
                acc = __builtin_amdgcn_mfma_f32_16x16x32_bf16(af, bf, acc, 0, 0, 0);
            }
            const int col = n0 + lr;
            const float bias = b2[col];
            #pragma unroll
            for (int r = 0; r < 4; ++r) {
                int row = m0 + lg * 4 + r;
                if (row < S_) {
                    int o = row * LDH + col;
                    hf[o] = acc[r] + bias + hf[o];
                }
            }
        }
    }
    __syncthreads();

    // ---- 8. LN2: hf -> out --------------------------------------------
    {
        const int wv = t >> 6, d = t & 63;
        const float g = ln2g[d], bb = ln2b[d];
        for (int i = 0; i < 6; ++i) {
            int r = wv + 8 * i;
            if (r < S_) {
                float v = hf[r * LDH + d];
                float s = v, s2 = v * v;
                #pragma unroll
                for (int off = 32; off; off >>= 1) {
                    s  += __shfl_xor(s, off);
                    s2 += __shfl_xor(s2, off);
                }
                float mean = s * (1.0f / 64.0f);
                float var  = s2 * (1.0f / 64.0f) - mean * mean;
                float nv = (v - mean) * rsqrtf(var + 1e-5f);
                out[(size_t)b * (S_ * D_) + r * 64 + d] = nv * g + bb;
            }
        }
    }
}

extern "C" void kernel_launch(void* const* d_in, const int* in_sizes, int n_in,
                              void* d_out, int out_size, void* d_ws, size_t ws_size,
                              hipStream_t stream) {
    const float* x    = (const float*)d_in[0];
    const float* Wq   = (const float*)d_in[1];
    const float* bq   = (const float*)d_in[2];
    const float* Wk   = (const float*)d_in[3];
    const float* bk   = (const float*)d_in[4];
    const float* Wv   = (const float*)d_in[5];
    const float* bv   = (const float*)d_in[6];
    const float* Wo   = (const float*)d_in[7];
    const float* bo   = (const float*)d_in[8];
    const float* ln1g = (const float*)d_in[9];
    const float* ln1b = (const float*)d_in[10];
    const float* W1   = (const float*)d_in[11];
    const float* b1   = (const float*)d_in[12];
    const float* W2   = (const float*)d_in[13];
    const float* b2   = (const float*)d_in[14];
    const float* ln2g = (const float*)d_in[15];
    const float* ln2b = (const float*)d_in[16];
    float* out = (float*)d_out;

    hipLaunchKernelGGL(prep_kernel, dim3(64), dim3(256), 0, stream,
                       Wq, Wk, Wv, Wo, W1, W2, d_ws);
    hipLaunchKernelGGL(encoder_kernel, dim3(NB), dim3(512), 0, stream,
                       x, bq, bk, bv, bo, ln1g, ln1b, b1, b2, ln2g, ln2b,
                       d_ws, out);
}